// Round 14
// baseline (834.464 us; speedup 1.0000x reference)
//
#include <hip/hip_runtime.h>

#define NN 50000
#define NE 800000
#define EPSB 1e-5f
#define NTILE 12500

typedef __attribute__((ext_vector_type(8))) short bf16x8;
typedef __attribute__((ext_vector_type(8))) unsigned short ushort8;
typedef __attribute__((ext_vector_type(4))) float f32x4;

__device__ __forceinline__ float sigm(float x){ return 1.0f/(1.0f+__expf(-x)); }
__device__ __forceinline__ float silu_(float x){ return x/(1.0f+__expf(-x)); }
__device__ __forceinline__ unsigned int cvt2(float lo, float hi){
  unsigned int r;
  asm("v_cvt_pk_bf16_f32 %0, %1, %2" : "=v"(r) : "v"(lo), "v"(hi));
  return r;
}
__device__ __forceinline__ unsigned short f2bf(float x){
  return (unsigned short)cvt2(x, 0.f);
}
__device__ __forceinline__ float bf2f(unsigned short b){
  return __uint_as_float(((unsigned int)b)<<16);
}
__device__ __forceinline__ ushort8 pack8(float a0,float a1,float a2,float a3,
                                         float a4,float a5,float a6,float a7){
  union { unsigned int u[4]; ushort8 s; } z;
  z.u[0]=cvt2(a0,a1); z.u[1]=cvt2(a2,a3); z.u[2]=cvt2(a4,a5); z.u[3]=cvt2(a6,a7);
  return z.s;
}
__device__ __forceinline__ ushort8 sum8(ushort8 a, ushort8 b){
  return pack8(bf2f(a[0])+bf2f(b[0]), bf2f(a[1])+bf2f(b[1]),
               bf2f(a[2])+bf2f(b[2]), bf2f(a[3])+bf2f(b[3]),
               bf2f(a[4])+bf2f(b[4]), bf2f(a[5])+bf2f(b[5]),
               bf2f(a[6])+bf2f(b[6]), bf2f(a[7])+bf2f(b[7]));
}

// ---------------- prep ----------------

__global__ __launch_bounds__(256) void k_deg(const int* __restrict__ src,
                                             int* __restrict__ deg){
  int e = blockIdx.x*256 + threadIdx.x;
  if (e < NE) atomicAdd(&deg[src[e]], 1);
}

__global__ __launch_bounds__(1024) void k_scan(const int* __restrict__ deg,
    int* __restrict__ cursor, float* __restrict__ invd){
  __shared__ int wsum[16];
  __shared__ int sbase;
  if (threadIdx.x == 0) sbase = 0;
  __syncthreads();
  const int lane = threadIdx.x & 63, wid = threadIdx.x >> 6;
  for (int start = 0; start < NN; start += 1024){
    int n = start + (int)threadIdx.x;
    int v = (n < NN) ? deg[n] : 0;
    int x = v;
    #pragma unroll
    for (int d=1; d<64; d<<=1){
      int y = __shfl_up(x, d);
      if (lane >= d) x += y;
    }
    if (lane == 63) wsum[wid] = x;
    __syncthreads();
    if (threadIdx.x < 16){
      int s = wsum[threadIdx.x];
      #pragma unroll
      for (int d=1; d<16; d<<=1){
        int y = __shfl_up(s, d);
        if ((int)threadIdx.x >= d) s += y;
      }
      wsum[threadIdx.x] = s;
    }
    __syncthreads();
    int excl = sbase + ((wid>0)? wsum[wid-1] : 0) + (x - v);
    if (n < NN){
      cursor[n] = excl;
      invd[n] = 1.0f / fmaxf((float)v, 1.0f);
    }
    __syncthreads();
    if (threadIdx.x == 0) sbase += wsum[15];
    __syncthreads();
  }
}

__global__ __launch_bounds__(256) void k_scatter(const int* __restrict__ src,
    const int* __restrict__ dst, int* __restrict__ cursor,
    int* __restrict__ perm, int* __restrict__ ssrc, int* __restrict__ sdst){
  int e = blockIdx.x*256 + threadIdx.x;
  if (e < NE){
    int s = src[e];
    int pos = atomicAdd(&cursor[s], 1);
    perm[pos] = e;
    ssrc[pos] = s;
    sdst[pos] = dst[e];
  }
}

// pre-convert all 15 weight mats (Wv 3x4 + We 3x1) to bf16, XOR-swizzled
__global__ __launch_bounds__(256) void k_prepW(const float* __restrict__ Wv,
    const float* __restrict__ We,
    unsigned short* __restrict__ wvs, unsigned short* __restrict__ wes){
  const int m = blockIdx.x;
  const float* S = (m < 12) ? (Wv + m*4096) : (We + (m-12)*4096);
  unsigned short* O = (m < 12) ? (wvs + m*4096) : (wes + (m-12)*4096);
  int t = threadIdx.x;
  #pragma unroll
  for (int p=0; p<2; ++p){
    int c = t + p*256;
    int row = c>>3, cc = c&7;
    const float4* sp = (const float4*)(S + row*64 + cc*8);
    float4 a = sp[0], b = sp[1];
    ushort8 v = pack8(a.x,a.y,a.z,a.w,b.x,b.y,b.z,b.w);
    *(ushort8*)((char*)O + ((row*128 + cc*16) ^ ((row&7)<<4))) = v;
  }
}

// ---------------- node linears (MFMA) + fused h-update ----------------
// Tables: x1 f32 [N][64]; x3T bf16 [N][64]; dstT bf16 [N][128] = [x4 | x2].
// MODE 1 zeroes agg after reading it.
template<int MODE>
__global__ __launch_bounds__(256) void k_nodelin(const float* __restrict__ xin,
    float* __restrict__ h, float* __restrict__ x1, float* __restrict__ agg,
    const float* __restrict__ invd, const float* __restrict__ coefp,
    const unsigned short* __restrict__ wvs, const float* __restrict__ bvl,
    unsigned short* __restrict__ x3T, unsigned short* __restrict__ dstT){
  __shared__ unsigned short shb[4096];
  __shared__ unsigned short sW[4096];
  const int n0 = blockIdx.x*64;
  const int t = threadIdx.x;
  #pragma unroll
  for (int p=0; p<2; ++p){
    int c = t + p*256;
    int row = c>>3, cc = c&7;
    int n = n0 + row;
    ushort8 v = {0,0,0,0,0,0,0,0};
    if (n < NN){
      unsigned base = (unsigned)n*64u + (unsigned)cc*8u;
      float4 a, b;
      if (MODE == 0){
        const float4* xp = (const float4*)(xin + base);
        a = xp[0]; b = xp[1];
        a.x=silu_(a.x); a.y=silu_(a.y); a.z=silu_(a.z); a.w=silu_(a.w);
        b.x=silu_(b.x); b.y=silu_(b.y); b.z=silu_(b.z); b.w=silu_(b.w);
        float4* hp = (float4*)(h + base);
        hp[0] = a; hp[1] = b;
      } else {
        float4* hp = (float4*)(h + base);
        a = hp[0]; b = hp[1];
        const float4* xp = (const float4*)(x1 + base);
        float4* gp = (float4*)(agg + base);
        float iv = invd[n];
        float4 xa = xp[0], xb4 = xp[1], ga = gp[0], gb = gp[1];
        float4 z = make_float4(0.f,0.f,0.f,0.f);
        gp[0] = z; gp[1] = z;
        float4 s0 = *(const float4*)(coefp + cc*8);
        float4 s1v = *(const float4*)(coefp + cc*8 + 4);
        float4 h0 = *(const float4*)(coefp + 64 + cc*8);
        float4 h1 = *(const float4*)(coefp + 64 + cc*8 + 4);
        a.x += silu_((xa.x + ga.x*iv)*s0.x + h0.x);
        a.y += silu_((xa.y + ga.y*iv)*s0.y + h0.y);
        a.z += silu_((xa.z + ga.z*iv)*s0.z + h0.z);
        a.w += silu_((xa.w + ga.w*iv)*s0.w + h0.w);
        b.x += silu_((xb4.x + gb.x*iv)*s1v.x + h1.x);
        b.y += silu_((xb4.y + gb.y*iv)*s1v.y + h1.y);
        b.z += silu_((xb4.z + gb.z*iv)*s1v.z + h1.z);
        b.w += silu_((xb4.w + gb.w*iv)*s1v.w + h1.w);
        hp[0] = a; hp[1] = b;
      }
      v = pack8(a.x,a.y,a.z,a.w,b.x,b.y,b.z,b.w);
    }
    *(ushort8*)((char*)shb + ((row*128 + cc*16) ^ ((row&7)<<4))) = v;
  }
  __syncthreads();
  const int wid = t>>6, lane = t&63, g = lane>>4, ln = lane&15;
  const int arow = wid*16 + ln;
  bf16x8 afr0 = *(bf16x8*)((char*)shb + ((arow*128 +  0 + g*16) ^ ((arow&7)<<4)));
  bf16x8 afr1 = *(bf16x8*)((char*)shb + ((arow*128 + 64 + g*16) ^ ((arow&7)<<4)));
  for (int k=0; k<4; ++k){
    __syncthreads();
    ((ushort8*)sW)[t]     = ((const ushort8*)(wvs + k*4096))[t];
    ((ushort8*)sW)[t+256] = ((const ushort8*)(wvs + k*4096))[t+256];
    __syncthreads();
    #pragma unroll
    for (int ft=0; ft<4; ++ft){
      int brow = ft*16 + ln;
      bf16x8 b0 = *(bf16x8*)((char*)sW + ((brow*128 +  0 + g*16) ^ ((brow&7)<<4)));
      bf16x8 b1 = *(bf16x8*)((char*)sW + ((brow*128 + 64 + g*16) ^ ((brow&7)<<4)));
      f32x4 c = {0.f,0.f,0.f,0.f};
      c = __builtin_amdgcn_mfma_f32_16x16x32_bf16(afr0, b0, c, 0,0,0);
      c = __builtin_amdgcn_mfma_f32_16x16x32_bf16(afr1, b1, c, 0,0,0);
      float bias = bvl[k*64 + brow];
      #pragma unroll
      for (int r=0; r<4; ++r){
        int n = n0 + wid*16 + g*4 + r;
        if (n < NN){
          float val = c[r] + bias;
          if (k == 0)      x1 [(unsigned)n*64u  + (unsigned)brow] = val;
          else if (k == 1) dstT[(unsigned)n*128u + 64u + (unsigned)brow] = f2bf(val); // x2
          else if (k == 2) x3T[(unsigned)n*64u  + (unsigned)brow] = f2bf(val);        // x3
          else             dstT[(unsigned)n*128u + (unsigned)brow] = f2bf(val);       // x4
        }
      }
    }
  }
}

// ---------------- edge pass A (persistent, MFMA, src-sorted, no u storage) ----------------
// grid 1024 blocks x 256 thr; each block loops tiles of 64 edges.
// We (old+new) staged ONCE per block. dst-gathers hit interleaved [x4|x2] rows.
template<int FIRST>
__global__ __launch_bounds__(256) void k_edgeA(const float* __restrict__ ea,
    unsigned short* __restrict__ wb16,
    const int* __restrict__ perm, const int* __restrict__ ssrc,
    const int* __restrict__ sdst,
    const unsigned short* __restrict__ wesO, const unsigned short* __restrict__ wesN,
    const float* __restrict__ beO, const float* __restrict__ beN,
    const unsigned short* __restrict__ x3o, const unsigned short* __restrict__ dstO,
    const unsigned short* __restrict__ x3n, const unsigned short* __restrict__ dstN,
    const float* __restrict__ coefp,
    float* __restrict__ agg, float* __restrict__ esum, float* __restrict__ esq){
  __shared__ unsigned short sWeO[4096], sWeN[4096];  // staged once
  __shared__ unsigned short swb[4096];               // w tile
  __shared__ unsigned short sxs[4096];               // x34 -> x2
  __shared__ int sidx[128];
  const int t = threadIdx.x;
  const int row0 = t>>3, cc8 = t&7, rr1 = row0+32;
  const int wid = t>>6, lane = t&63, g = lane>>4, ln = lane&15;
  const int arow = wid*16 + ln;

  if (!FIRST){
    ((ushort8*)sWeO)[t]     = ((const ushort8*)wesO)[t];
    ((ushort8*)sWeO)[t+256] = ((const ushort8*)wesO)[t+256];
  }
  ((ushort8*)sWeN)[t]     = ((const ushort8*)wesN)[t];
  ((ushort8*)sWeN)[t+256] = ((const ushort8*)wesN)[t+256];

  float scp[4], shp[4], beo[4], ben[4];
  #pragma unroll
  for (int ft=0; ft<4; ++ft){
    ben[ft] = beN[ft*16+ln];
    if (!FIRST){
      scp[ft] = coefp[128 + ft*16 + ln];
      shp[ft] = coefp[192 + ft*16 + ln];
      beo[ft] = beO[ft*16 + ln];
    }
  }

  for (int tile = blockIdx.x; tile < NTILE; tile += gridDim.x){
    const int e0 = tile*64;
    const unsigned ebase = (unsigned)e0*64u;
    __syncthreads();   // prior-tile LDS reads done (also covers We stage, iter 0)

    if (t < 64) sidx[t] = ssrc[e0+t];
    else if (t < 128) sidx[t] = sdst[e0+t-64];
    unsigned sA0=(unsigned)ssrc[e0+row0], dA0=(unsigned)sdst[e0+row0];
    unsigned sA1=(unsigned)ssrc[e0+rr1],  dA1=(unsigned)sdst[e0+rr1];

    // stage w tile
    #pragma unroll
    for (int p=0; p<2; ++p){
      int c = t + p*256;
      int row = row0 + p*32;
      ushort8 v;
      if (FIRST){
        unsigned esrc = (unsigned)perm[e0 + row];
        const float4* sp = (const float4*)(ea + esrc*64u + (unsigned)cc8*8u);
        float4 a = sp[0], b = sp[1];
        v = pack8(silu_(a.x),silu_(a.y),silu_(a.z),silu_(a.w),
                  silu_(b.x),silu_(b.y),silu_(b.z),silu_(b.w));
        ((ushort8*)(wb16 + ebase))[c] = v;
      } else {
        v = ((const ushort8*)(wb16 + ebase))[c];
      }
      *(ushort8*)((char*)swb + ((row*128 + cc8*16) ^ ((row&7)<<4))) = v;
    }
    // stage x34 sums (old gen for MID, new for FIRST); x4 = dstT first half
    {
      const unsigned short* X3 = FIRST ? x3n : x3o;
      const unsigned short* DT = FIRST ? dstN : dstO;
      ushort8 a0 = *(const ushort8*)(X3 + sA0*64u  + (unsigned)cc8*8u);
      ushort8 b0 = *(const ushort8*)(DT + dA0*128u + (unsigned)cc8*8u);
      ushort8 a1 = *(const ushort8*)(X3 + sA1*64u  + (unsigned)cc8*8u);
      ushort8 b1 = *(const ushort8*)(DT + dA1*128u + (unsigned)cc8*8u);
      *(ushort8*)((char*)sxs + ((row0*128 + cc8*16) ^ ((row0&7)<<4))) = sum8(a0,b0);
      *(ushort8*)((char*)sxs + ((rr1*128  + cc8*16) ^ ((rr1&7)<<4)))  = sum8(a1,b1);
    }
    __syncthreads();   // B1

    if (!FIRST){
      // GEMM1: u_old -> w_new
      bf16x8 afr0 = *(bf16x8*)((char*)swb + ((arow*128 +  0 + g*16) ^ ((arow&7)<<4)));
      bf16x8 afr1 = *(bf16x8*)((char*)swb + ((arow*128 + 64 + g*16) ^ ((arow&7)<<4)));
      f32x4 cacc[4];
      #pragma unroll
      for (int ft=0; ft<4; ++ft){
        int brow = ft*16 + ln;
        bf16x8 b0 = *(bf16x8*)((char*)sWeO + ((brow*128 +  0 + g*16) ^ ((brow&7)<<4)));
        bf16x8 b1 = *(bf16x8*)((char*)sWeO + ((brow*128 + 64 + g*16) ^ ((brow&7)<<4)));
        f32x4 c = {0.f,0.f,0.f,0.f};
        c = __builtin_amdgcn_mfma_f32_16x16x32_bf16(afr0, b0, c, 0,0,0);
        c = __builtin_amdgcn_mfma_f32_16x16x32_bf16(afr1, b1, c, 0,0,0);
        cacc[ft] = c;
      }
      float wnew[4][4];
      #pragma unroll
      for (int r=0; r<4; ++r){
        int row = wid*16 + g*4 + r;
        #pragma unroll
        for (int ft=0; ft<4; ++ft){
          int f = ft*16 + ln;
          unsigned short a34 = *(unsigned short*)((char*)sxs + ((row*128 + f*2) ^ ((row&7)<<4)));
          unsigned short wo  = *(unsigned short*)((char*)swb + ((row*128 + f*2) ^ ((row&7)<<4)));
          float u = cacc[ft][r] + beo[ft] + bf2f(a34);
          wnew[ft][r] = bf2f(wo) + silu_(u*scp[ft] + shp[ft]);
        }
      }
      __syncthreads();   // B2: swb/sxs reads done

      // scatter w_new -> swb; restage sxs <- x34new
      #pragma unroll
      for (int r=0; r<4; ++r){
        int row = wid*16 + g*4 + r;
        #pragma unroll
        for (int ft=0; ft<4; ++ft){
          int f = ft*16 + ln;
          *(unsigned short*)((char*)swb + ((row*128 + f*2) ^ ((row&7)<<4))) = f2bf(wnew[ft][r]);
        }
      }
      {
        ushort8 a0 = *(const ushort8*)(x3n + sA0*64u  + (unsigned)cc8*8u);
        ushort8 b0 = *(const ushort8*)(dstN + dA0*128u + (unsigned)cc8*8u);
        ushort8 a1 = *(const ushort8*)(x3n + sA1*64u  + (unsigned)cc8*8u);
        ushort8 b1 = *(const ushort8*)(dstN + dA1*128u + (unsigned)cc8*8u);
        *(ushort8*)((char*)sxs + ((row0*128 + cc8*16) ^ ((row0&7)<<4))) = sum8(a0,b0);
        *(ushort8*)((char*)sxs + ((rr1*128  + cc8*16) ^ ((rr1&7)<<4)))  = sum8(a1,b1);
      }
      __syncthreads();   // B3

      // coalesced w_new -> wb16
      #pragma unroll
      for (int p=0; p<2; ++p){
        int c = t + p*256;
        int row = row0 + p*32;
        ushort8 v = *(ushort8*)((char*)swb + ((row*128 + cc8*16) ^ ((row&7)<<4)));
        ((ushort8*)(wb16 + ebase))[c] = v;
      }
    }

    // GEMM2: u_new stats
    {
      bf16x8 afr0 = *(bf16x8*)((char*)swb + ((arow*128 +  0 + g*16) ^ ((arow&7)<<4)));
      bf16x8 afr1 = *(bf16x8*)((char*)swb + ((arow*128 + 64 + g*16) ^ ((arow&7)<<4)));
      f32x4 cacc[4];
      #pragma unroll
      for (int ft=0; ft<4; ++ft){
        int brow = ft*16 + ln;
        bf16x8 b0 = *(bf16x8*)((char*)sWeN + ((brow*128 +  0 + g*16) ^ ((brow&7)<<4)));
        bf16x8 b1 = *(bf16x8*)((char*)sWeN + ((brow*128 + 64 + g*16) ^ ((brow&7)<<4)));
        f32x4 c = {0.f,0.f,0.f,0.f};
        c = __builtin_amdgcn_mfma_f32_16x16x32_bf16(afr0, b0, c, 0,0,0);
        c = __builtin_amdgcn_mfma_f32_16x16x32_bf16(afr1, b1, c, 0,0,0);
        cacc[ft] = c;
      }
      float s1[4]={0.f,0.f,0.f,0.f}, s2[4]={0.f,0.f,0.f,0.f};
      #pragma unroll
      for (int r=0; r<4; ++r){
        int row = wid*16 + g*4 + r;
        #pragma unroll
        for (int ft=0; ft<4; ++ft){
          int f = ft*16 + ln;
          unsigned short a34 = *(unsigned short*)((char*)sxs + ((row*128 + f*2) ^ ((row&7)<<4)));
          float u = cacc[ft][r] + ben[ft] + bf2f(a34);
          s1[ft] += u; s2[ft] += u*u;
        }
      }
      #pragma unroll
      for (int ft=0; ft<4; ++ft){
        s1[ft] += __shfl_xor(s1[ft], 16); s1[ft] += __shfl_xor(s1[ft], 32);
        s2[ft] += __shfl_xor(s2[ft], 16); s2[ft] += __shfl_xor(s2[ft], 32);
      }
      if (g == 0){
        int slot = ((tile<<2) + wid) & 63;
        #pragma unroll
        for (int ft=0; ft<4; ++ft){
          atomicAdd(&esum[(slot<<6) + ft*16 + ln], s1[ft]);
          atomicAdd(&esq [(slot<<6) + ft*16 + ln], s2[ft]);
        }
      }
    }
    __syncthreads();   // B4: sxs reads done

    // stage x2 (dstT second half — row already L2-hot from x4 gather)
    {
      const unsigned short* DT = dstN;
      ushort8 v0 = *(const ushort8*)(DT + dA0*128u + 64u + (unsigned)cc8*8u);
      ushort8 v1 = *(const ushort8*)(DT + dA1*128u + 64u + (unsigned)cc8*8u);
      *(ushort8*)((char*)sxs + ((row0*128 + cc8*16) ^ ((row0&7)<<4))) = v0;
      *(ushort8*)((char*)sxs + ((rr1*128  + cc8*16) ^ ((rr1&7)<<4)))  = v1;
    }
    __syncthreads();   // B5

    // gated messages, run-length aggregated (ssrc sorted)
    {
      const int el0 = wid<<4;
      unsigned curs = (unsigned)sidx[el0];
      float run = 0.f;
      #pragma unroll
      for (int j=0; j<16; ++j){
        int el = el0 + j;
        unsigned s = (unsigned)sidx[el];
        if (s != curs){
          atomicAdd(&agg[curs*64u + (unsigned)lane], run);
          run = 0.f; curs = s;
        }
        unsigned short wv = *(unsigned short*)((char*)swb + ((el*128 + lane*2) ^ ((el&7)<<4)));
        unsigned short xv = *(unsigned short*)((char*)sxs + ((el*128 + lane*2) ^ ((el&7)<<4)));
        run += sigm(bf2f(wv)) * bf2f(xv);
      }
      atomicAdd(&agg[curs*64u + (unsigned)lane], run);
    }
  }
}

// ---------------- final edge output (persistent): wout[perm] = w2 + silu(bn(u2)) ----------------
__global__ __launch_bounds__(256) void k_edgeFin(const unsigned short* __restrict__ wb16,
    const int* __restrict__ perm, const int* __restrict__ ssrc,
    const int* __restrict__ sdst,
    const unsigned short* __restrict__ wes2, const float* __restrict__ be2,
    const unsigned short* __restrict__ x3c, const unsigned short* __restrict__ dstC,
    const float* __restrict__ coef2, float* __restrict__ wout){
  __shared__ unsigned short sWe[4096];
  __shared__ unsigned short swb[4096];
  __shared__ unsigned short sxs[4096];
  const int t = threadIdx.x;
  const int row0 = t>>3, cc8 = t&7, rr1 = row0+32;
  const int wid = t>>6, lane = t&63, g = lane>>4, ln = lane&15;
  const int arow = wid*16 + ln;

  ((ushort8*)sWe)[t]     = ((const ushort8*)wes2)[t];
  ((ushort8*)sWe)[t+256] = ((const ushort8*)wes2)[t+256];
  float scp[4], shp[4], be4[4];
  #pragma unroll
  for (int ft=0; ft<4; ++ft){
    scp[ft] = coef2[128 + ft*16 + ln];
    shp[ft] = coef2[192 + ft*16 + ln];
    be4[ft] = be2[ft*16 + ln];
  }

  for (int tile = blockIdx.x; tile < NTILE; tile += gridDim.x){
    const int e0 = tile*64;
    const unsigned ebase = (unsigned)e0*64u;
    __syncthreads();

    unsigned sA0=(unsigned)ssrc[e0+row0], dA0=(unsigned)sdst[e0+row0];
    unsigned sA1=(unsigned)ssrc[e0+rr1],  dA1=(unsigned)sdst[e0+rr1];

    #pragma unroll
    for (int p=0; p<2; ++p){
      int c = t + p*256;
      int row = row0 + p*32;
      ushort8 v = ((const ushort8*)(wb16 + ebase))[c];
      *(ushort8*)((char*)swb + ((row*128 + cc8*16) ^ ((row&7)<<4))) = v;
    }
    {
      ushort8 a0 = *(const ushort8*)(x3c + sA0*64u  + (unsigned)cc8*8u);
      ushort8 b0 = *(const ushort8*)(dstC + dA0*128u + (unsigned)cc8*8u);
      ushort8 a1 = *(const ushort8*)(x3c + sA1*64u  + (unsigned)cc8*8u);
      ushort8 b1 = *(const ushort8*)(dstC + dA1*128u + (unsigned)cc8*8u);
      *(ushort8*)((char*)sxs + ((row0*128 + cc8*16) ^ ((row0&7)<<4))) = sum8(a0,b0);
      *(ushort8*)((char*)sxs + ((rr1*128  + cc8*16) ^ ((rr1&7)<<4)))  = sum8(a1,b1);
    }
    __syncthreads();   // B1

    bf16x8 afr0 = *(bf16x8*)((char*)swb + ((arow*128 +  0 + g*16) ^ ((arow&7)<<4)));
    bf16x8 afr1 = *(bf16x8*)((char*)swb + ((arow*128 + 64 + g*16) ^ ((arow&7)<<4)));
    f32x4 cacc[4];
    #pragma unroll
    for (int ft=0; ft<4; ++ft){
      int brow = ft*16 + ln;
      bf16x8 b0 = *(bf16x8*)((char*)sWe + ((brow*128 +  0 + g*16) ^ ((brow&7)<<4)));
      bf16x8 b1 = *(bf16x8*)((char*)sWe + ((brow*128 + 64 + g*16) ^ ((brow&7)<<4)));
      f32x4 c = {0.f,0.f,0.f,0.f};
      c = __builtin_amdgcn_mfma_f32_16x16x32_bf16(afr0, b0, c, 0,0,0);
      c = __builtin_amdgcn_mfma_f32_16x16x32_bf16(afr1, b1, c, 0,0,0);
      cacc[ft] = c;
    }
    #pragma unroll
    for (int r=0; r<4; ++r){
      int row = wid*16 + g*4 + r;
      #pragma unroll
      for (int ft=0; ft<4; ++ft){
        int f = ft*16 + ln;
        unsigned short* slot = (unsigned short*)((char*)sxs + ((row*128 + f*2) ^ ((row&7)<<4)));
        unsigned short wo = *(unsigned short*)((char*)swb + ((row*128 + f*2) ^ ((row&7)<<4)));
        float u = cacc[ft][r] + be4[ft] + bf2f(*slot);
        float o = bf2f(wo) + silu_(u*scp[ft] + shp[ft]);
        *slot = f2bf(o);
      }
    }
    __syncthreads();   // B2

    #pragma unroll
    for (int p=0; p<2; ++p){
      int c = t + p*256;
      int row = row0 + p*32;
      ushort8 v = *(ushort8*)((char*)sxs + ((row*128 + cc8*16) ^ ((row&7)<<4)));
      unsigned eid = (unsigned)perm[e0 + row];
      float4 oa = make_float4(bf2f(v[0]),bf2f(v[1]),bf2f(v[2]),bf2f(v[3]));
      float4 ob = make_float4(bf2f(v[4]),bf2f(v[5]),bf2f(v[6]),bf2f(v[7]));
      float4* wp = (float4*)(wout + eid*64u + (unsigned)cc8*8u);
      wp[0] = oa; wp[1] = ob;
    }
  }
}

// ---------------- node BN stats over t = x1 + agg*invdeg ----------------
__global__ __launch_bounds__(256) void k_nodestats(const float* __restrict__ x1,
    const float* __restrict__ agg, const float* __restrict__ invd,
    float* __restrict__ nsum, float* __restrict__ nsq){
  const int f = threadIdx.x & 63, sub = threadIdx.x >> 6;
  float s1=0.f, s2=0.f;
  for (int n = blockIdx.x*4 + sub; n < NN; n += gridDim.x*4){
    unsigned off = (unsigned)n*64u + (unsigned)f;
    float t = x1[off] + agg[off]*invd[n];
    s1 += t; s2 += t*t;
  }
  __shared__ float red[4][64][2];
  red[sub][f][0]=s1; red[sub][f][1]=s2;
  __syncthreads();
  if (sub==0){
    float a1=red[0][f][0]+red[1][f][0]+red[2][f][0]+red[3][f][0];
    float a2=red[0][f][1]+red[1][f][1]+red[2][f][1]+red[3][f][1];
    int slot = blockIdx.x & 63;
    atomicAdd(&nsum[(slot<<6)+f], a1);
    atomicAdd(&nsq[(slot<<6)+f], a2);
  }
}

// ---------------- finalize both BN -> per-layer coef slot; zero stats after ----------------
__global__ void k_finalize(float* __restrict__ nsum, float* __restrict__ nsq,
    float* __restrict__ esum, float* __restrict__ esq,
    const float* __restrict__ gn, const float* __restrict__ bn,
    const float* __restrict__ ge, const float* __restrict__ beb,
    float* __restrict__ coef){
  int t = threadIdx.x;
  if (t >= 128) return;
  int f = t & 63;
  float* S1 = (t<64)? nsum : esum;
  float* S2 = (t<64)? nsq  : esq;
  float cnt = (t<64)? (float)NN : (float)NE;
  float s1=0.f, s2=0.f;
  for (int k=0;k<64;++k){ s1 += S1[(k<<6)+f]; s2 += S2[(k<<6)+f]; }
  for (int k=0;k<64;++k){ S1[(k<<6)+f]=0.f; S2[(k<<6)+f]=0.f; }
  float mu = s1/cnt;
  float var = s2/cnt - mu*mu;
  float rstd = rsqrtf(var + EPSB);
  float g = (t<64)? gn[f] : ge[f];
  float b = (t<64)? bn[f] : beb[f];
  float sc = g*rstd, sh = b - mu*sc;
  coef[((t<64)?0:2)*64 + f] = sc;
  coef[((t<64)?1:3)*64 + f] = sh;
}

// ---------------- final node update: h += silu(bn(t)) ----------------
__global__ __launch_bounds__(256) void k_nodeupd(const float* __restrict__ x1,
    const float* __restrict__ agg, const float* __restrict__ invd,
    const float* __restrict__ coef, float* __restrict__ h){
  unsigned i = blockIdx.x*256u + threadIdx.x;
  if (i >= NN*64u) return;
  unsigned n = i>>6, f = i&63u;
  float t = x1[i] + agg[i]*invd[n];
  float v = t*coef[f] + coef[64+f];
  h[i] += silu_(v);
}

// ---------------- launch ----------------

extern "C" void kernel_launch(void* const* d_in, const int* in_sizes, int n_in,
                              void* d_out, int out_size, void* d_ws, size_t ws_size,
                              hipStream_t stream){
  const float* x      = (const float*)d_in[0];
  const int*   eidx   = (const int*)d_in[1];
  const float* eattr  = (const float*)d_in[2];
  const float* Wv     = (const float*)d_in[3];
  const float* bv     = (const float*)d_in[4];
  const float* We     = (const float*)d_in[5];
  const float* be     = (const float*)d_in[6];
  const float* g_node = (const float*)d_in[7];
  const float* b_node = (const float*)d_in[8];
  const float* g_edge = (const float*)d_in[9];
  const float* b_edge = (const float*)d_in[10];
  const int* src = eidx;
  const int* dst = eidx + NE;

  float* hout = (float*)d_out;                 // [N][64] live node state (f32)
  float* wout = hout + (size_t)NN*64;          // [E][64] final edge output (f32)

  float* W    = (float*)d_ws;
  float* x1   = W;                                           // 3.2M f32
  float* agg  = W + 3200000;                                 // 3.2M f32
  float* nsum = W + 6400000;                                 // 4x4096 contiguous
  float* nsq  = W + 6404096;
  float* esum = W + 6408192;
  float* esq  = W + 6412288;
  float* coef = W + 6416384;                                 // 3*256
  float* invd = W + 6417152;                                 // 50000
  int*   deg  = (int*)(W + 6467152);                         // 50000
  unsigned short* xb   = (unsigned short*)(W + 6517152);     // 2 gens x 3*N64 bf16
  unsigned short* wvs  = (unsigned short*)(W + 16200000);    // 12*4096 bf16 swz
  unsigned short* wes  = (unsigned short*)(W + 16230000);    // 3*4096 bf16 swz
  unsigned short* wb16 = (unsigned short*)(W + 16240000);    // E*64 bf16 (sorted)
  int* perm   = (int*)(W + 41840000);                        // E
  int* ssrc   = (int*)(W + 42640000);                        // E
  int* sdst   = (int*)(W + 43440000);                        // E
  int* cursor = (int*)(W + 44240000);                        // N

  hipMemsetAsync(deg, 0, NN*sizeof(int), stream);
  hipMemsetAsync(agg, 0, (3200000 + 4*4096)*sizeof(float), stream);
  k_deg<<<3125, 256, 0, stream>>>(src, deg);
  k_scan<<<1, 1024, 0, stream>>>(deg, cursor, invd);
  k_scatter<<<3125, 256, 0, stream>>>(src, dst, cursor, perm, ssrc, sdst);
  k_prepW<<<15, 256, 0, stream>>>(Wv, We, wvs, wes);

  const unsigned N64 = NN*64u;
  for (int l=0; l<3; ++l){
    int gc = l & 1, go = (l-1) & 1;
    unsigned short* xbc = xb + (size_t)gc*3*N64;   // gen c: x3T (N64) + dstT (2*N64)
    unsigned short* xbo = xb + (size_t)go*3*N64;
    unsigned short* x3c = xbc,      * dtc = xbc + N64;
    unsigned short* x3o = xbo,      * dto = xbo + N64;
    const float* cprev = coef + (l-1)*256;
    if (l == 0)
      k_nodelin<0><<<782, 256, 0, stream>>>(x, hout, x1, agg, invd, coef,
          wvs + l*16384, bv + l*256, x3c, dtc);
    else
      k_nodelin<1><<<782, 256, 0, stream>>>(x, hout, x1, agg, invd, cprev,
          wvs + l*16384, bv + l*256, x3c, dtc);
    if (l == 0)
      k_edgeA<1><<<1024, 256, 0, stream>>>(eattr, wb16, perm, ssrc, sdst,
          wes, wes, be, be,
          x3o, dto,                      // unused for FIRST
          x3c, dtc,
          coef, agg, esum, esq);
    else
      k_edgeA<0><<<1024, 256, 0, stream>>>(eattr, wb16, perm, ssrc, sdst,
          wes + (l-1)*4096, wes + l*4096, be + (l-1)*64, be + l*64,
          x3o, dto,
          x3c, dtc,
          cprev, agg, esum, esq);
    k_nodestats<<<256, 256, 0, stream>>>(x1, agg, invd, nsum, nsq);
    k_finalize<<<1, 128, 0, stream>>>(nsum, nsq, esum, esq,
        g_node + l*64, b_node + l*64, g_edge + l*64, b_edge + l*64, coef + l*256);
  }
  // final state updates (layer 2 coef; layer-2 tables are gen 0)
  unsigned short* xb2 = xb;   // gen 0
  k_nodeupd<<<12500, 256, 0, stream>>>(x1, agg, invd, coef + 512, hout);
  k_edgeFin<<<1024, 256, 0, stream>>>(wb16, perm, ssrc, sdst,
      wes + 2*4096, be + 2*64, xb2, xb2 + N64, coef + 512, wout);
}

// Round 15
// 719.624 us; speedup vs baseline: 1.1596x; 1.1596x over previous
//
#include <hip/hip_runtime.h>

#define NN 50000
#define NE 800000
#define EPSB 1e-5f

typedef __attribute__((ext_vector_type(8))) short bf16x8;
typedef __attribute__((ext_vector_type(8))) unsigned short ushort8;
typedef __attribute__((ext_vector_type(4))) float f32x4;

__device__ __forceinline__ float sigm(float x){ return 1.0f/(1.0f+__expf(-x)); }
__device__ __forceinline__ float silu_(float x){ return x/(1.0f+__expf(-x)); }
__device__ __forceinline__ unsigned int cvt2(float lo, float hi){
  unsigned int r;
  asm("v_cvt_pk_bf16_f32 %0, %1, %2" : "=v"(r) : "v"(lo), "v"(hi));
  return r;
}
__device__ __forceinline__ unsigned short f2bf(float x){
  return (unsigned short)cvt2(x, 0.f);
}
__device__ __forceinline__ float bf2f(unsigned short b){
  return __uint_as_float(((unsigned int)b)<<16);
}
__device__ __forceinline__ ushort8 pack8(float a0,float a1,float a2,float a3,
                                         float a4,float a5,float a6,float a7){
  union { unsigned int u[4]; ushort8 s; } z;
  z.u[0]=cvt2(a0,a1); z.u[1]=cvt2(a2,a3); z.u[2]=cvt2(a4,a5); z.u[3]=cvt2(a6,a7);
  return z.s;
}
// sum two bf16x8 rows -> bf16x8
__device__ __forceinline__ ushort8 sum8(ushort8 a, ushort8 b){
  return pack8(bf2f(a[0])+bf2f(b[0]), bf2f(a[1])+bf2f(b[1]),
               bf2f(a[2])+bf2f(b[2]), bf2f(a[3])+bf2f(b[3]),
               bf2f(a[4])+bf2f(b[4]), bf2f(a[5])+bf2f(b[5]),
               bf2f(a[6])+bf2f(b[6]), bf2f(a[7])+bf2f(b[7]));
}

// ---------------- prep ----------------

__global__ __launch_bounds__(256) void k_deg(const int* __restrict__ src,
                                             int* __restrict__ deg){
  int e = blockIdx.x*256 + threadIdx.x;
  if (e < NE) atomicAdd(&deg[src[e]], 1);
}

__global__ __launch_bounds__(1024) void k_scan(const int* __restrict__ deg,
    int* __restrict__ cursor, float* __restrict__ invd){
  __shared__ int wsum[16];
  __shared__ int sbase;
  if (threadIdx.x == 0) sbase = 0;
  __syncthreads();
  const int lane = threadIdx.x & 63, wid = threadIdx.x >> 6;
  for (int start = 0; start < NN; start += 1024){
    int n = start + (int)threadIdx.x;
    int v = (n < NN) ? deg[n] : 0;
    int x = v;
    #pragma unroll
    for (int d=1; d<64; d<<=1){
      int y = __shfl_up(x, d);
      if (lane >= d) x += y;
    }
    if (lane == 63) wsum[wid] = x;
    __syncthreads();
    if (threadIdx.x < 16){
      int s = wsum[threadIdx.x];
      #pragma unroll
      for (int d=1; d<16; d<<=1){
        int y = __shfl_up(s, d);
        if ((int)threadIdx.x >= d) s += y;
      }
      wsum[threadIdx.x] = s;
    }
    __syncthreads();
    int excl = sbase + ((wid>0)? wsum[wid-1] : 0) + (x - v);
    if (n < NN){
      cursor[n] = excl;
      invd[n] = 1.0f / fmaxf((float)v, 1.0f);
    }
    __syncthreads();
    if (threadIdx.x == 0) sbase += wsum[15];
    __syncthreads();
  }
}

__global__ __launch_bounds__(256) void k_scatter(const int* __restrict__ src,
    const int* __restrict__ dst, int* __restrict__ cursor,
    int* __restrict__ perm, int* __restrict__ ssrc, int* __restrict__ sdst){
  int e = blockIdx.x*256 + threadIdx.x;
  if (e < NE){
    int s = src[e];
    int pos = atomicAdd(&cursor[s], 1);
    perm[pos] = e;
    ssrc[pos] = s;
    sdst[pos] = dst[e];
  }
}

// pre-convert all 15 weight mats (Wv 3x4 + We 3x1) to bf16, XOR-swizzled
__global__ __launch_bounds__(256) void k_prepW(const float* __restrict__ Wv,
    const float* __restrict__ We,
    unsigned short* __restrict__ wvs, unsigned short* __restrict__ wes){
  const int m = blockIdx.x;
  const float* S = (m < 12) ? (Wv + m*4096) : (We + (m-12)*4096);
  unsigned short* O = (m < 12) ? (wvs + m*4096) : (wes + (m-12)*4096);
  int t = threadIdx.x;
  #pragma unroll
  for (int p=0; p<2; ++p){
    int c = t + p*256;
    int row = c>>3, cc = c&7;
    const float4* sp = (const float4*)(S + row*64 + cc*8);
    float4 a = sp[0], b = sp[1];
    ushort8 v = pack8(a.x,a.y,a.z,a.w,b.x,b.y,b.z,b.w);
    *(ushort8*)((char*)O + ((row*128 + cc*16) ^ ((row&7)<<4))) = v;
  }
}

// ---------------- node linears (MFMA) + fused h-update ----------------
// MODE 1 also zeroes agg after reading it (replaces per-layer memset).
template<int MODE>
__global__ __launch_bounds__(256) void k_nodelin(const float* __restrict__ xin,
    float* __restrict__ h, float* __restrict__ x1, float* __restrict__ agg,
    const float* __restrict__ invd, const float* __restrict__ coefp,
    const unsigned short* __restrict__ wvs, const float* __restrict__ bvl,
    unsigned short* __restrict__ xb){
  __shared__ unsigned short shb[4096];   // h tile bf16 swizzled
  __shared__ unsigned short sW[4096];    // current weight mat
  const int n0 = blockIdx.x*64;
  const int t = threadIdx.x;
  #pragma unroll
  for (int p=0; p<2; ++p){
    int c = t + p*256;
    int row = c>>3, cc = c&7;
    int n = n0 + row;
    ushort8 v = {0,0,0,0,0,0,0,0};
    if (n < NN){
      unsigned base = (unsigned)n*64u + (unsigned)cc*8u;
      float4 a, b;
      if (MODE == 0){
        const float4* xp = (const float4*)(xin + base);
        a = xp[0]; b = xp[1];
        a.x=silu_(a.x); a.y=silu_(a.y); a.z=silu_(a.z); a.w=silu_(a.w);
        b.x=silu_(b.x); b.y=silu_(b.y); b.z=silu_(b.z); b.w=silu_(b.w);
        float4* hp = (float4*)(h + base);
        hp[0] = a; hp[1] = b;
      } else {
        float4* hp = (float4*)(h + base);
        a = hp[0]; b = hp[1];
        const float4* xp = (const float4*)(x1 + base);
        float4* gp = (float4*)(agg + base);
        float iv = invd[n];
        float4 xa = xp[0], xb4 = xp[1], ga = gp[0], gb = gp[1];
        float4 z = make_float4(0.f,0.f,0.f,0.f);
        gp[0] = z; gp[1] = z;   // zero agg for this layer's edgeA
        float4 s0 = *(const float4*)(coefp + cc*8);
        float4 s1v = *(const float4*)(coefp + cc*8 + 4);
        float4 h0 = *(const float4*)(coefp + 64 + cc*8);
        float4 h1 = *(const float4*)(coefp + 64 + cc*8 + 4);
        a.x += silu_((xa.x + ga.x*iv)*s0.x + h0.x);
        a.y += silu_((xa.y + ga.y*iv)*s0.y + h0.y);
        a.z += silu_((xa.z + ga.z*iv)*s0.z + h0.z);
        a.w += silu_((xa.w + ga.w*iv)*s0.w + h0.w);
        b.x += silu_((xb4.x + gb.x*iv)*s1v.x + h1.x);
        b.y += silu_((xb4.y + gb.y*iv)*s1v.y + h1.y);
        b.z += silu_((xb4.z + gb.z*iv)*s1v.z + h1.z);
        b.w += silu_((xb4.w + gb.w*iv)*s1v.w + h1.w);
        hp[0] = a; hp[1] = b;
      }
      v = pack8(a.x,a.y,a.z,a.w,b.x,b.y,b.z,b.w);
    }
    *(ushort8*)((char*)shb + ((row*128 + cc*16) ^ ((row&7)<<4))) = v;
  }
  __syncthreads();
  const int wid = t>>6, lane = t&63, g = lane>>4, ln = lane&15;
  const int arow = wid*16 + ln;
  bf16x8 afr0 = *(bf16x8*)((char*)shb + ((arow*128 +  0 + g*16) ^ ((arow&7)<<4)));
  bf16x8 afr1 = *(bf16x8*)((char*)shb + ((arow*128 + 64 + g*16) ^ ((arow&7)<<4)));
  for (int k=0; k<4; ++k){
    __syncthreads();
    ((ushort8*)sW)[t]     = ((const ushort8*)(wvs + k*4096))[t];
    ((ushort8*)sW)[t+256] = ((const ushort8*)(wvs + k*4096))[t+256];
    __syncthreads();
    #pragma unroll
    for (int ft=0; ft<4; ++ft){
      int brow = ft*16 + ln;
      bf16x8 b0 = *(bf16x8*)((char*)sW + ((brow*128 +  0 + g*16) ^ ((brow&7)<<4)));
      bf16x8 b1 = *(bf16x8*)((char*)sW + ((brow*128 + 64 + g*16) ^ ((brow&7)<<4)));
      f32x4 c = {0.f,0.f,0.f,0.f};
      c = __builtin_amdgcn_mfma_f32_16x16x32_bf16(afr0, b0, c, 0,0,0);
      c = __builtin_amdgcn_mfma_f32_16x16x32_bf16(afr1, b1, c, 0,0,0);
      float bias = bvl[k*64 + brow];
      #pragma unroll
      for (int r=0; r<4; ++r){
        int n = n0 + wid*16 + g*4 + r;
        if (n < NN){
          float val = c[r] + bias;
          unsigned off = (unsigned)n*64u + (unsigned)brow;
          if (k == 0) x1[off] = val;
          else xb[(unsigned)(k-1)*(NN*64u) + off] = f2bf(val);
        }
      }
    }
  }
}

// ---------------- edge pass A (MFMA, src-sorted), NO u storage ----------------
// MID (FIRST=0): recompute u_old = w_old@WeO^T+beO+x34o, apply BN_prev -> w_new
// in-place in LDS; write w_new to wb16; second GEMM u_new stats; messages.
// 256 threads, 64 edges/block, 25KB LDS.
template<int FIRST>
__global__ __launch_bounds__(256) void k_edgeA(const float* __restrict__ ea,
    unsigned short* __restrict__ wb16,
    const int* __restrict__ perm, const int* __restrict__ ssrc,
    const int* __restrict__ sdst,
    const unsigned short* __restrict__ wesO, const unsigned short* __restrict__ wesN,
    const float* __restrict__ beO, const float* __restrict__ beN,
    const unsigned short* __restrict__ x3o, const unsigned short* __restrict__ x4o,
    const unsigned short* __restrict__ x2n, const unsigned short* __restrict__ x3n,
    const unsigned short* __restrict__ x4n, const float* __restrict__ coefp,
    float* __restrict__ agg, float* __restrict__ esum, float* __restrict__ esq){
  __shared__ unsigned short sWb[4096];   // We (old, then new)
  __shared__ unsigned short swb[4096];   // w tile (old, then new in-place)
  __shared__ unsigned short sxs[4096];   // x34old -> x34new -> x2
  __shared__ int sidx[128];
  const int e0 = blockIdx.x*64;
  const unsigned ebase = (unsigned)e0*64u;
  const int t = threadIdx.x;
  const int row0 = t>>3, cc8 = t&7, rr1 = row0+32;
  const int wid = t>>6, lane = t&63, g = lane>>4, ln = lane&15;
  const int arow = wid*16 + ln;

  unsigned sA0=(unsigned)ssrc[e0+row0], dA0=(unsigned)sdst[e0+row0];
  unsigned sA1=(unsigned)ssrc[e0+rr1],  dA1=(unsigned)sdst[e0+rr1];

  if (t < 64) sidx[t] = ssrc[e0+t];
  else if (t < 128) sidx[t] = sdst[e0+t-64];

  // phase 1: stage We (old gen for MID, new for FIRST)
  {
    const unsigned short* wesP = FIRST ? wesN : wesO;
    ((ushort8*)sWb)[t]     = ((const ushort8*)wesP)[t];
    ((ushort8*)sWb)[t+256] = ((const ushort8*)wesP)[t+256];
  }
  // stage w tile (FIRST: silu(eattr[perm]) + wb16 write; MID: wb16 read)
  #pragma unroll
  for (int p=0; p<2; ++p){
    int c = t + p*256;
    int row = row0 + p*32;
    ushort8 v;
    if (FIRST){
      unsigned esrc = (unsigned)perm[e0 + row];
      const float4* sp = (const float4*)(ea + esrc*64u + (unsigned)cc8*8u);
      float4 a = sp[0], b = sp[1];
      v = pack8(silu_(a.x),silu_(a.y),silu_(a.z),silu_(a.w),
                silu_(b.x),silu_(b.y),silu_(b.z),silu_(b.w));
      ((ushort8*)(wb16 + ebase))[c] = v;
    } else {
      v = ((const ushort8*)(wb16 + ebase))[c];
    }
    *(ushort8*)((char*)swb + ((row*128 + cc8*16) ^ ((row&7)<<4))) = v;
  }
  // stage x34 sums (old gen for MID, new for FIRST)
  {
    const unsigned short* X3 = FIRST ? x3n : x3o;
    const unsigned short* X4 = FIRST ? x4n : x4o;
    ushort8 a0 = *(const ushort8*)(X3 + sA0*64u + (unsigned)cc8*8u);
    ushort8 b0 = *(const ushort8*)(X4 + dA0*64u + (unsigned)cc8*8u);
    ushort8 a1 = *(const ushort8*)(X3 + sA1*64u + (unsigned)cc8*8u);
    ushort8 b1 = *(const ushort8*)(X4 + dA1*64u + (unsigned)cc8*8u);
    *(ushort8*)((char*)sxs + ((row0*128 + cc8*16) ^ ((row0&7)<<4))) = sum8(a0,b0);
    *(ushort8*)((char*)sxs + ((rr1*128  + cc8*16) ^ ((rr1&7)<<4)))  = sum8(a1,b1);
  }
  __syncthreads();   // B1

  if (!FIRST){
    // GEMM1: u_old, then w_new = w_old + silu(u_old*sc+sh)
    bf16x8 afr0 = *(bf16x8*)((char*)swb + ((arow*128 +  0 + g*16) ^ ((arow&7)<<4)));
    bf16x8 afr1 = *(bf16x8*)((char*)swb + ((arow*128 + 64 + g*16) ^ ((arow&7)<<4)));
    bf16x8 bfr[4][2];
    #pragma unroll
    for (int ft=0; ft<4; ++ft){
      int brow = ft*16 + ln;
      bfr[ft][0] = *(bf16x8*)((char*)sWb + ((brow*128 +  0 + g*16) ^ ((brow&7)<<4)));
      bfr[ft][1] = *(bf16x8*)((char*)sWb + ((brow*128 + 64 + g*16) ^ ((brow&7)<<4)));
    }
    f32x4 cacc[4];
    #pragma unroll
    for (int ft=0; ft<4; ++ft){
      f32x4 c = {0.f,0.f,0.f,0.f};
      c = __builtin_amdgcn_mfma_f32_16x16x32_bf16(afr0, bfr[ft][0], c, 0,0,0);
      c = __builtin_amdgcn_mfma_f32_16x16x32_bf16(afr1, bfr[ft][1], c, 0,0,0);
      cacc[ft] = c;
    }
    float scp[4], shp[4], beo[4], wnew[4][4];
    #pragma unroll
    for (int ft=0; ft<4; ++ft){
      scp[ft] = coefp[128 + ft*16 + ln];
      shp[ft] = coefp[192 + ft*16 + ln];
      beo[ft] = beO[ft*16 + ln];
    }
    #pragma unroll
    for (int r=0; r<4; ++r){
      int row = wid*16 + g*4 + r;
      #pragma unroll
      for (int ft=0; ft<4; ++ft){
        int f = ft*16 + ln;
        unsigned short a34 = *(unsigned short*)((char*)sxs + ((row*128 + f*2) ^ ((row&7)<<4)));
        unsigned short wo  = *(unsigned short*)((char*)swb + ((row*128 + f*2) ^ ((row&7)<<4)));
        float u = cacc[ft][r] + beo[ft] + bf2f(a34);
        wnew[ft][r] = bf2f(wo) + silu_(u*scp[ft] + shp[ft]);
      }
    }
    __syncthreads();   // B2: all swb/sWb/sxs reads done

    // write w_new into swb (C-layout, bijective); restage sWb=WeN, sxs=x34new
    #pragma unroll
    for (int r=0; r<4; ++r){
      int row = wid*16 + g*4 + r;
      #pragma unroll
      for (int ft=0; ft<4; ++ft){
        int f = ft*16 + ln;
        *(unsigned short*)((char*)swb + ((row*128 + f*2) ^ ((row&7)<<4))) = f2bf(wnew[ft][r]);
      }
    }
    ((ushort8*)sWb)[t]     = ((const ushort8*)wesN)[t];
    ((ushort8*)sWb)[t+256] = ((const ushort8*)wesN)[t+256];
    {
      ushort8 a0 = *(const ushort8*)(x3n + sA0*64u + (unsigned)cc8*8u);
      ushort8 b0 = *(const ushort8*)(x4n + dA0*64u + (unsigned)cc8*8u);
      ushort8 a1 = *(const ushort8*)(x3n + sA1*64u + (unsigned)cc8*8u);
      ushort8 b1 = *(const ushort8*)(x4n + dA1*64u + (unsigned)cc8*8u);
      *(ushort8*)((char*)sxs + ((row0*128 + cc8*16) ^ ((row0&7)<<4))) = sum8(a0,b0);
      *(ushort8*)((char*)sxs + ((rr1*128  + cc8*16) ^ ((rr1&7)<<4)))  = sum8(a1,b1);
    }
    __syncthreads();   // B3: w_new/WeN/x34new staged

    // coalesced w_new -> wb16
    #pragma unroll
    for (int p=0; p<2; ++p){
      int c = t + p*256;
      int row = row0 + p*32;
      ushort8 v = *(ushort8*)((char*)swb + ((row*128 + cc8*16) ^ ((row&7)<<4)));
      ((ushort8*)(wb16 + ebase))[c] = v;
    }
  }

  // GEMM2 (or the only GEMM for FIRST): u_new stats
  bf16x8 afr0 = *(bf16x8*)((char*)swb + ((arow*128 +  0 + g*16) ^ ((arow&7)<<4)));
  bf16x8 afr1 = *(bf16x8*)((char*)swb + ((arow*128 + 64 + g*16) ^ ((arow&7)<<4)));
  bf16x8 bfr[4][2];
  #pragma unroll
  for (int ft=0; ft<4; ++ft){
    int brow = ft*16 + ln;
    bfr[ft][0] = *(bf16x8*)((char*)sWb + ((brow*128 +  0 + g*16) ^ ((brow&7)<<4)));
    bfr[ft][1] = *(bf16x8*)((char*)sWb + ((brow*128 + 64 + g*16) ^ ((brow&7)<<4)));
  }
  f32x4 cacc[4];
  #pragma unroll
  for (int ft=0; ft<4; ++ft){
    f32x4 c = {0.f,0.f,0.f,0.f};
    c = __builtin_amdgcn_mfma_f32_16x16x32_bf16(afr0, bfr[ft][0], c, 0,0,0);
    c = __builtin_amdgcn_mfma_f32_16x16x32_bf16(afr1, bfr[ft][1], c, 0,0,0);
    cacc[ft] = c;
  }
  float ben[4], s1[4]={0.f,0.f,0.f,0.f}, s2[4]={0.f,0.f,0.f,0.f};
  #pragma unroll
  for (int ft=0; ft<4; ++ft) ben[ft] = beN[ft*16+ln];
  #pragma unroll
  for (int r=0; r<4; ++r){
    int row = wid*16 + g*4 + r;
    #pragma unroll
    for (int ft=0; ft<4; ++ft){
      int f = ft*16 + ln;
      unsigned short a34 = *(unsigned short*)((char*)sxs + ((row*128 + f*2) ^ ((row&7)<<4)));
      float u = cacc[ft][r] + ben[ft] + bf2f(a34);
      s1[ft] += u; s2[ft] += u*u;
    }
  }
  #pragma unroll
  for (int ft=0; ft<4; ++ft){
    s1[ft] += __shfl_xor(s1[ft], 16); s1[ft] += __shfl_xor(s1[ft], 32);
    s2[ft] += __shfl_xor(s2[ft], 16); s2[ft] += __shfl_xor(s2[ft], 32);
  }
  if (g == 0){
    int slot = ((blockIdx.x<<2) + wid) & 63;
    #pragma unroll
    for (int ft=0; ft<4; ++ft){
      atomicAdd(&esum[(slot<<6) + ft*16 + ln], s1[ft]);
      atomicAdd(&esq [(slot<<6) + ft*16 + ln], s2[ft]);
    }
  }
  __syncthreads();   // B4: sxs reads done

  // stage x2[dst]
  {
    ushort8 v0 = *(const ushort8*)(x2n + dA0*64u + (unsigned)cc8*8u);
    ushort8 v1 = *(const ushort8*)(x2n + dA1*64u + (unsigned)cc8*8u);
    *(ushort8*)((char*)sxs + ((row0*128 + cc8*16) ^ ((row0&7)<<4))) = v0;
    *(ushort8*)((char*)sxs + ((rr1*128  + cc8*16) ^ ((rr1&7)<<4)))  = v1;
  }
  __syncthreads();   // B5

  // gated messages, run-length aggregated (ssrc sorted); uses w_new in swb
  {
    const int el0 = wid<<4;
    unsigned curs = (unsigned)sidx[el0];
    float run = 0.f;
    #pragma unroll
    for (int j=0; j<16; ++j){
      int el = el0 + j;
      unsigned s = (unsigned)sidx[el];
      if (s != curs){
        atomicAdd(&agg[curs*64u + (unsigned)lane], run);
        run = 0.f; curs = s;
      }
      unsigned short wv = *(unsigned short*)((char*)swb + ((el*128 + lane*2) ^ ((el&7)<<4)));
      unsigned short xv = *(unsigned short*)((char*)sxs + ((el*128 + lane*2) ^ ((el&7)<<4)));
      run += sigm(bf2f(wv)) * bf2f(xv);
    }
    atomicAdd(&agg[curs*64u + (unsigned)lane], run);
  }
}

// ---------------- final edge output: wout[perm] = w2 + silu(bn(recomputed u2)) ----------------
__global__ __launch_bounds__(256) void k_edgeFin(const unsigned short* __restrict__ wb16,
    const int* __restrict__ perm, const int* __restrict__ ssrc,
    const int* __restrict__ sdst,
    const unsigned short* __restrict__ wes2, const float* __restrict__ be2,
    const unsigned short* __restrict__ x3c, const unsigned short* __restrict__ x4c,
    const float* __restrict__ coef2, float* __restrict__ wout){
  __shared__ unsigned short sWb[4096];
  __shared__ unsigned short swb[4096];
  __shared__ unsigned short sxs[4096];
  const int e0 = blockIdx.x*64;
  const unsigned ebase = (unsigned)e0*64u;
  const int t = threadIdx.x;
  const int row0 = t>>3, cc8 = t&7, rr1 = row0+32;
  const int wid = t>>6, lane = t&63, g = lane>>4, ln = lane&15;
  const int arow = wid*16 + ln;

  unsigned sA0=(unsigned)ssrc[e0+row0], dA0=(unsigned)sdst[e0+row0];
  unsigned sA1=(unsigned)ssrc[e0+rr1],  dA1=(unsigned)sdst[e0+rr1];

  ((ushort8*)sWb)[t]     = ((const ushort8*)wes2)[t];
  ((ushort8*)sWb)[t+256] = ((const ushort8*)wes2)[t+256];
  #pragma unroll
  for (int p=0; p<2; ++p){
    int c = t + p*256;
    int row = row0 + p*32;
    ushort8 v = ((const ushort8*)(wb16 + ebase))[c];
    *(ushort8*)((char*)swb + ((row*128 + cc8*16) ^ ((row&7)<<4))) = v;
  }
  {
    ushort8 a0 = *(const ushort8*)(x3c + sA0*64u + (unsigned)cc8*8u);
    ushort8 b0 = *(const ushort8*)(x4c + dA0*64u + (unsigned)cc8*8u);
    ushort8 a1 = *(const ushort8*)(x3c + sA1*64u + (unsigned)cc8*8u);
    ushort8 b1 = *(const ushort8*)(x4c + dA1*64u + (unsigned)cc8*8u);
    *(ushort8*)((char*)sxs + ((row0*128 + cc8*16) ^ ((row0&7)<<4))) = sum8(a0,b0);
    *(ushort8*)((char*)sxs + ((rr1*128  + cc8*16) ^ ((rr1&7)<<4)))  = sum8(a1,b1);
  }
  __syncthreads();   // B1

  bf16x8 afr0 = *(bf16x8*)((char*)swb + ((arow*128 +  0 + g*16) ^ ((arow&7)<<4)));
  bf16x8 afr1 = *(bf16x8*)((char*)swb + ((arow*128 + 64 + g*16) ^ ((arow&7)<<4)));
  bf16x8 bfr[4][2];
  #pragma unroll
  for (int ft=0; ft<4; ++ft){
    int brow = ft*16 + ln;
    bfr[ft][0] = *(bf16x8*)((char*)sWb + ((brow*128 +  0 + g*16) ^ ((brow&7)<<4)));
    bfr[ft][1] = *(bf16x8*)((char*)sWb + ((brow*128 + 64 + g*16) ^ ((brow&7)<<4)));
  }
  f32x4 cacc[4];
  #pragma unroll
  for (int ft=0; ft<4; ++ft){
    f32x4 c = {0.f,0.f,0.f,0.f};
    c = __builtin_amdgcn_mfma_f32_16x16x32_bf16(afr0, bfr[ft][0], c, 0,0,0);
    c = __builtin_amdgcn_mfma_f32_16x16x32_bf16(afr1, bfr[ft][1], c, 0,0,0);
    cacc[ft] = c;
  }
  float scp[4], shp[4], be4[4];
  #pragma unroll
  for (int ft=0; ft<4; ++ft){
    scp[ft] = coef2[128 + ft*16 + ln];
    shp[ft] = coef2[192 + ft*16 + ln];
    be4[ft] = be2[ft*16 + ln];
  }
  #pragma unroll
  for (int r=0; r<4; ++r){
    int row = wid*16 + g*4 + r;
    #pragma unroll
    for (int ft=0; ft<4; ++ft){
      int f = ft*16 + ln;
      unsigned short* slot = (unsigned short*)((char*)sxs + ((row*128 + f*2) ^ ((row&7)<<4)));
      unsigned short wo = *(unsigned short*)((char*)swb + ((row*128 + f*2) ^ ((row&7)<<4)));
      float u = cacc[ft][r] + be4[ft] + bf2f(*slot);
      float o = bf2f(wo) + silu_(u*scp[ft] + shp[ft]);
      *slot = f2bf(o);          // in-place (same thread reads then writes)
    }
  }
  __syncthreads();   // B2

  // coalesced read + perm scatter (f32, 32B per thread-chunk)
  #pragma unroll
  for (int p=0; p<2; ++p){
    int c = t + p*256;
    int row = row0 + p*32;
    ushort8 v = *(ushort8*)((char*)sxs + ((row*128 + cc8*16) ^ ((row&7)<<4)));
    unsigned eid = (unsigned)perm[e0 + row];
    float4 oa = make_float4(bf2f(v[0]),bf2f(v[1]),bf2f(v[2]),bf2f(v[3]));
    float4 ob = make_float4(bf2f(v[4]),bf2f(v[5]),bf2f(v[6]),bf2f(v[7]));
    float4* wp = (float4*)(wout + eid*64u + (unsigned)cc8*8u);
    wp[0] = oa; wp[1] = ob;
  }
}

// ---------------- node BN stats over t = x1 + agg*invdeg ----------------
__global__ __launch_bounds__(256) void k_nodestats(const float* __restrict__ x1,
    const float* __restrict__ agg, const float* __restrict__ invd,
    float* __restrict__ nsum, float* __restrict__ nsq){
  const int f = threadIdx.x & 63, sub = threadIdx.x >> 6;
  float s1=0.f, s2=0.f;
  for (int n = blockIdx.x*4 + sub; n < NN; n += gridDim.x*4){
    unsigned off = (unsigned)n*64u + (unsigned)f;
    float t = x1[off] + agg[off]*invd[n];
    s1 += t; s2 += t*t;
  }
  __shared__ float red[4][64][2];
  red[sub][f][0]=s1; red[sub][f][1]=s2;
  __syncthreads();
  if (sub==0){
    float a1=red[0][f][0]+red[1][f][0]+red[2][f][0]+red[3][f][0];
    float a2=red[0][f][1]+red[1][f][1]+red[2][f][1]+red[3][f][1];
    int slot = blockIdx.x & 63;
    atomicAdd(&nsum[(slot<<6)+f], a1);
    atomicAdd(&nsq[(slot<<6)+f], a2);
  }
}

// ---------------- finalize both BN -> per-layer coef slot; zero stats after ----------------
__global__ void k_finalize(float* __restrict__ nsum, float* __restrict__ nsq,
    float* __restrict__ esum, float* __restrict__ esq,
    const float* __restrict__ gn, const float* __restrict__ bn,
    const float* __restrict__ ge, const float* __restrict__ beb,
    float* __restrict__ coef){
  int t = threadIdx.x;
  if (t >= 128) return;
  int f = t & 63;
  float* S1 = (t<64)? nsum : esum;
  float* S2 = (t<64)? nsq  : esq;
  float cnt = (t<64)? (float)NN : (float)NE;
  float s1=0.f, s2=0.f;
  for (int k=0;k<64;++k){ s1 += S1[(k<<6)+f]; s2 += S2[(k<<6)+f]; }
  for (int k=0;k<64;++k){ S1[(k<<6)+f]=0.f; S2[(k<<6)+f]=0.f; }
  float mu = s1/cnt;
  float var = s2/cnt - mu*mu;
  float rstd = rsqrtf(var + EPSB);
  float g = (t<64)? gn[f] : ge[f];
  float b = (t<64)? bn[f] : beb[f];
  float sc = g*rstd, sh = b - mu*sc;
  coef[((t<64)?0:2)*64 + f] = sc;
  coef[((t<64)?1:3)*64 + f] = sh;
}

// ---------------- final node update: h += silu(bn(t)) ----------------
__global__ __launch_bounds__(256) void k_nodeupd(const float* __restrict__ x1,
    const float* __restrict__ agg, const float* __restrict__ invd,
    const float* __restrict__ coef, float* __restrict__ h){
  unsigned i = blockIdx.x*256u + threadIdx.x;
  if (i >= NN*64u) return;
  unsigned n = i>>6, f = i&63u;
  float t = x1[i] + agg[i]*invd[n];
  float v = t*coef[f] + coef[64+f];
  h[i] += silu_(v);
}

// ---------------- launch ----------------

extern "C" void kernel_launch(void* const* d_in, const int* in_sizes, int n_in,
                              void* d_out, int out_size, void* d_ws, size_t ws_size,
                              hipStream_t stream){
  const float* x      = (const float*)d_in[0];
  const int*   eidx   = (const int*)d_in[1];
  const float* eattr  = (const float*)d_in[2];
  const float* Wv     = (const float*)d_in[3];
  const float* bv     = (const float*)d_in[4];
  const float* We     = (const float*)d_in[5];
  const float* be     = (const float*)d_in[6];
  const float* g_node = (const float*)d_in[7];
  const float* b_node = (const float*)d_in[8];
  const float* g_edge = (const float*)d_in[9];
  const float* b_edge = (const float*)d_in[10];
  const int* src = eidx;
  const int* dst = eidx + NE;

  float* hout = (float*)d_out;                 // [N][64] live node state (f32)
  float* wout = hout + (size_t)NN*64;          // [E][64] final edge output (f32)

  float* W    = (float*)d_ws;
  float* x1   = W;                                           // 3.2M f32
  float* agg  = W + 3200000;                                 // 3.2M f32
  float* nsum = W + 6400000;                                 // 4x4096 contiguous
  float* nsq  = W + 6404096;
  float* esum = W + 6408192;
  float* esq  = W + 6412288;
  float* coef = W + 6416384;                                 // 3*256
  float* invd = W + 6417152;                                 // 50000
  int*   deg  = (int*)(W + 6467152);                         // 50000
  unsigned short* xb   = (unsigned short*)(W + 6517152);     // 2 gens x 3 x N*64 bf16
  unsigned short* wvs  = (unsigned short*)(W + 16200000);    // 12*4096 bf16 swz
  unsigned short* wes  = (unsigned short*)(W + 16230000);    // 3*4096 bf16 swz
  unsigned short* wb16 = (unsigned short*)(W + 16240000);    // E*64 bf16 (sorted)
  int* perm   = (int*)(W + 41840000);                        // E
  int* ssrc   = (int*)(W + 42640000);                        // E
  int* sdst   = (int*)(W + 43440000);                        // E
  int* cursor = (int*)(W + 44240000);                        // N

  hipMemsetAsync(deg, 0, NN*sizeof(int), stream);
  hipMemsetAsync(agg, 0, (3200000 + 4*4096)*sizeof(float), stream);
  k_deg<<<3125, 256, 0, stream>>>(src, deg);
  k_scan<<<1, 1024, 0, stream>>>(deg, cursor, invd);
  k_scatter<<<3125, 256, 0, stream>>>(src, dst, cursor, perm, ssrc, sdst);
  k_prepW<<<15, 256, 0, stream>>>(Wv, We, wvs, wes);

  const unsigned N64 = NN*64u;
  for (int l=0; l<3; ++l){
    int gc = l & 1, go = (l-1) & 1;
    unsigned short* xbc = xb + (size_t)gc*3*N64;
    unsigned short* xbo = xb + (size_t)go*3*N64;
    const float* cprev = coef + (l-1)*256;
    if (l == 0)
      k_nodelin<0><<<782, 256, 0, stream>>>(x, hout, x1, agg, invd, coef,
          wvs + l*16384, bv + l*256, xbc);
    else
      k_nodelin<1><<<782, 256, 0, stream>>>(x, hout, x1, agg, invd, cprev,
          wvs + l*16384, bv + l*256, xbc);
    if (l == 0)
      k_edgeA<1><<<12500, 256, 0, stream>>>(eattr, wb16, perm, ssrc, sdst,
          wes, wes, be, be,
          xbo + N64, xbo + 2*N64,            // unused for FIRST
          xbc, xbc + N64, xbc + 2*N64,
          coef, agg, esum, esq);
    else
      k_edgeA<0><<<12500, 256, 0, stream>>>(eattr, wb16, perm, ssrc, sdst,
          wes + (l-1)*4096, wes + l*4096, be + (l-1)*64, be + l*64,
          xbo + N64, xbo + 2*N64,
          xbc, xbc + N64, xbc + 2*N64,
          cprev, agg, esum, esq);
    k_nodestats<<<256, 256, 0, stream>>>(x1, agg, invd, nsum, nsq);
    k_finalize<<<1, 128, 0, stream>>>(nsum, nsq, esum, esq,
        g_node + l*64, b_node + l*64, g_edge + l*64, b_edge + l*64, coef + l*256);
  }
  // final state updates (layer 2 coef; layer-2 tables are gen 0)
  unsigned short* xb2 = xb;   // gen 0
  k_nodeupd<<<12500, 256, 0, stream>>>(x1, agg, invd, coef + 512, hout);
  k_edgeFin<<<12500, 256, 0, stream>>>(wb16, perm, ssrc, sdst,
      wes + 2*4096, be + 2*64, xb2 + N64, xb2 + 2*N64, coef + 512, wout);
}